// Round 2
// baseline (188.569 us; speedup 1.0000x reference)
//
#include <hip/hip_runtime.h>

// MeanConv: out = mask * (1/7) * sum_{k in 3,5,..,15} boxmean_k(x), edge padding.
// Edge-replicate padding == index clamping, so each box mean is a plain 2D box
// filter over clamped indices. All 7 box sums come from one 2D integral image
// per tile: 4 LDS reads per k, 28 per pixel. All I/O fp32 (per reference).

#define TILE  64
#define HALO  7
#define LW    (TILE + 2 * HALO)   // 78 raw tile width
#define PROWS (LW + 1)            // 79 (row 0 is the zero row)
#define PSTR  81                  // padded LDS stride (81 % 32 = 17, coprime with 32)
#define HH    4096
#define WW    4096

__global__ __launch_bounds__(256) void meanconv_kernel(
    const float* __restrict__ x, const float* __restrict__ mask,
    float* __restrict__ out)
{
    __shared__ float P[PROWS * PSTR];   // 79*81*4 = 25.6 KB
    const int tid = threadIdx.x;
    const int c0  = blockIdx.x * TILE;
    const int r0  = blockIdx.y * TILE;

    // --- load clamp-indexed raw tile into P[1..LW][1..LW] ---
    for (int idx = tid; idx < LW * LW; idx += 256) {
        int lr = idx / LW, lc = idx - lr * LW;
        int gr = r0 + lr - HALO; gr = min(max(gr, 0), HH - 1);
        int gc = c0 + lc - HALO; gc = min(max(gc, 0), WW - 1);
        P[(lr + 1) * PSTR + (lc + 1)] = x[gr * WW + gc];
    }
    // zero col 0 (rows 0..78) and row 0 (cols 0..78)
    if (tid < PROWS) P[tid * PSTR] = 0.0f;
    if (tid >= 128 && tid < 128 + LW + 1) P[tid - 128] = 0.0f;
    __syncthreads();

    // --- row-wise inclusive prefix over cols 1..LW, one thread per row ---
    if (tid < LW) {
        float run = 0.0f;
        const int base = (tid + 1) * PSTR;
        #pragma unroll 6
        for (int c = 1; c <= LW; ++c) { run += P[base + c]; P[base + c] = run; }
    }
    __syncthreads();

    // --- col-wise inclusive prefix over rows 1..LW, one thread per column ---
    if (tid < LW) {
        float run = 0.0f;
        const int c = tid + 1;
        #pragma unroll 6
        for (int r = 1; r <= LW; ++r) { run += P[r * PSTR + c]; P[r * PSTR + c] = run; }
    }
    __syncthreads();
    // Now P[a][b] = sum of raw[lr<a][lc<b]  (exclusive-style via the +1 offset).

    // --- per-pixel accumulation: 4 corner reads per k, 7 k's ---
    const int tx = tid & 63;   // column within tile -> stride-1 LDS reads per wave
    const int ty = tid >> 6;
    for (int rr = ty; rr < TILE; rr += 4) {
        const int A = rr + HALO;    // raw-row of this output pixel
        const int B = tx + HALO;    // raw-col
        float acc = 0.0f;
        #pragma unroll
        for (int p = 1; p <= 7; ++p) {
            const int k = 2 * p + 1;
            const float w = 1.0f / (7.0f * (float)(k * k));
            const float s = P[(A + p + 1) * PSTR + (B + p + 1)]
                          - P[(A - p)     * PSTR + (B + p + 1)]
                          - P[(A + p + 1) * PSTR + (B - p)]
                          + P[(A - p)     * PSTR + (B - p)];
            acc += w * s;
        }
        const int gr = r0 + rr, gc = c0 + tx;
        out[gr * WW + gc] = acc * mask[gr * WW + gc];
    }
}

extern "C" void kernel_launch(void* const* d_in, const int* in_sizes, int n_in,
                              void* d_out, int out_size, void* d_ws, size_t ws_size,
                              hipStream_t stream) {
    const float* x    = (const float*)d_in[0];
    const float* mask = (const float*)d_in[1];
    float*       out  = (float*)d_out;
    dim3 grid(WW / TILE, HH / TILE);
    meanconv_kernel<<<grid, 256, 0, stream>>>(x, mask, out);
}

// Round 3
// 187.617 us; speedup vs baseline: 1.0051x; 1.0051x over previous
//
#include <hip/hip_runtime.h>

// MeanConv: out = mask * (1/7) * sum_{k in 3,5,..,15} boxmean_k(x), edge padding.
// Per-tile 2D integral image in LDS; each of the 7 box sums = 4-corner diff.
// Pixel phase computes 4 consecutive-x pixels per thread so the per-row corner
// reads are constant offsets off one base -> compiler merges to ds_read2_b32
// (2 values/inst), halving LDS wave-instructions vs scalar b32.
// Left halo widened to 8 so staging uses 16B-aligned float4 global loads.

#define TILE  64
#define HALO  7
#define LHX   8            // left halo in x (8 for float4 alignment)
#define NCOL  80           // raw cols loaded: c0-8 .. c0+71
#define NROW  78           // raw rows loaded: r0-7 .. r0+70
#define PCOLS 81           // P cols 0..80 (col 0 is the zero col)
#define PROWS 79           // P rows 0..78 (row 0 is the zero row)
#define PSTR  83           // odd stride, 83%32=19: conflict-free column walks
#define HH    4096
#define WW    4096

__global__ __launch_bounds__(256) void meanconv_kernel(
    const float* __restrict__ x, const float* __restrict__ mask,
    float* __restrict__ out)
{
    __shared__ float P[PROWS * PSTR];   // 79*83*4 = 26.2 KB
    const int tid = threadIdx.x;
    const int c0  = blockIdx.x * TILE;
    const int r0  = blockIdx.y * TILE;

    // --- stage raw tile into P[1..78][1..80] (rows clamp; cols clamp only at x-edges) ---
    if (c0 >= LHX && c0 + (NCOL - LHX) <= WW) {
        // interior in x: cols c0-8 .. c0+71 all in range; aligned float4 loads
        for (int idx = tid; idx < NROW * (NCOL / 4); idx += 256) {
            int lr  = idx / (NCOL / 4);
            int lc4 = (idx - lr * (NCOL / 4)) * 4;
            int gr  = min(max(r0 + lr - HALO, 0), HH - 1);
            const float4 v = *(const float4*)&x[gr * WW + (c0 - LHX + lc4)];
            float* d = &P[(lr + 1) * PSTR + 1 + lc4];
            d[0] = v.x; d[1] = v.y; d[2] = v.z; d[3] = v.w;
        }
    } else {
        for (int idx = tid; idx < NROW * NCOL; idx += 256) {
            int lr = idx / NCOL, lc = idx - lr * NCOL;
            int gr = min(max(r0 + lr - HALO, 0), HH - 1);
            int gc = min(max(c0 - LHX + lc, 0), WW - 1);
            P[(lr + 1) * PSTR + 1 + lc] = x[gr * WW + gc];
        }
    }
    if (tid < PROWS) P[tid * PSTR] = 0.0f;                       // zero col
    if (tid >= 128 && tid < 128 + PCOLS) P[tid - 128] = 0.0f;    // zero row
    __syncthreads();

    // --- row-wise inclusive prefix over cols 1..80, one thread per row ---
    if (tid < NROW) {
        float run = 0.0f;
        const int base = (tid + 1) * PSTR;
        #pragma unroll 8
        for (int c = 1; c <= NCOL; ++c) { run += P[base + c]; P[base + c] = run; }
    }
    __syncthreads();

    // --- col-wise inclusive prefix over rows 1..78, one thread per column ---
    if (tid < NCOL) {
        float run = 0.0f;
        const int c = tid + 1;
        #pragma unroll 6
        for (int r = 1; r <= NROW; ++r) { run += P[r * PSTR + c]; P[r * PSTR + c] = run; }
    }
    __syncthreads();
    // P[a][b] = sum of raw[row < a][col < b].

    // --- pixel phase: 4 consecutive-x pixels per thread, 4 row-groups ---
    const int g  = tid & 15;          // column group (16 groups of 4 px)
    const int ty = tid >> 4;          // 16 row-threads
    const int B0 = 4 * g;             // first tile col of this thread
    #pragma unroll
    for (int j = 0; j < 4; ++j) {
        const int rr = ty + 16 * j;   // tile row
        const int A  = rr + HALO;     // raw row of the pixel
        float a0 = 0.f, a1 = 0.f, a2 = 0.f, a3 = 0.f;
        #pragma unroll
        for (int p = 1; p <= 7; ++p) {
            const int   k = 2 * p + 1;
            const float w = 1.0f / (7.0f * (float)(k * k));
            const float* rT = &P[(A - p) * PSTR];       // top corner row
            const float* rB = &P[(A + p + 1) * PSTR];   // bottom corner row
            const int cl = B0 + LHX - p;                // left P col for px 0
            const int cr = B0 + LHX + 1 + p;            // right P col for px 0
            a0 += w * (rB[cr + 0] - rT[cr + 0] - rB[cl + 0] + rT[cl + 0]);
            a1 += w * (rB[cr + 1] - rT[cr + 1] - rB[cl + 1] + rT[cl + 1]);
            a2 += w * (rB[cr + 2] - rT[cr + 2] - rB[cl + 2] + rT[cl + 2]);
            a3 += w * (rB[cr + 3] - rT[cr + 3] - rB[cl + 3] + rT[cl + 3]);
        }
        const int gr = r0 + rr, gc = c0 + B0;
        const float4 m = *(const float4*)&mask[gr * WW + gc];
        float4 o;
        o.x = a0 * m.x; o.y = a1 * m.y; o.z = a2 * m.z; o.w = a3 * m.w;
        *(float4*)&out[gr * WW + gc] = o;
    }
}

extern "C" void kernel_launch(void* const* d_in, const int* in_sizes, int n_in,
                              void* d_out, int out_size, void* d_ws, size_t ws_size,
                              hipStream_t stream) {
    const float* x    = (const float*)d_in[0];
    const float* mask = (const float*)d_in[1];
    float*       out  = (float*)d_out;
    dim3 grid(WW / TILE, HH / TILE);
    meanconv_kernel<<<grid, 256, 0, stream>>>(x, mask, out);
}

// Round 4
// 183.959 us; speedup vs baseline: 1.0251x; 1.0199x over previous
//
#include <hip/hip_runtime.h>

// MeanConv: out = mask * (1/7) * sum_{k in 3,5,..,15} boxmean_k(x), edge padding.
// Per-tile 2D integral image in LDS; each box sum = 4-corner difference.
// All phases fully parallel:
//   P1: stage+row-prefix fused — 20-float row segments in registers,
//       4-lane __shfl_up fixup, write prefixed rows to LDS. No serial walk.
//   P2: column prefix — 4 segments of <=20 rows per column, register prefix
//       + 4-lane shuffle fixup.
//   P3: 8 px/thread, corner reads merge to ds_read2_b32 + CSE dedup.
// Only 2 barriers. LDS 26.9 KB -> 6 blocks/CU.

#define TILE   64
#define HALO   7
#define LHX    8            // left halo (8 for float4 alignment)
#define NCOL   80           // staged cols: c0-8 .. c0+71
#define NROW   78           // staged rows: r0-7 .. r0+70
#define PSTR   83           // odd; 19 mod 32 -> conflict-free pixel/col patterns
#define PROWSA 81           // rows 0..78 used + 2 slack (safe predicated reads)
#define HH     4096
#define WW     4096

__global__ __launch_bounds__(256) void meanconv_kernel(
    const float* __restrict__ x, const float* __restrict__ mask,
    float* __restrict__ out)
{
    __shared__ float P[PROWSA * PSTR];   // 81*83*4 = 26892 B
    const int tid = threadIdx.x;
    const int c0  = blockIdx.x * TILE;
    const int r0  = blockIdx.y * TILE;

    // zero row 0 (cols 0..80); rows 1..78 written below, no race
    if (tid < 81) P[tid] = 0.0f;

    const bool xint = (c0 >= LHX) && (c0 - LHX + NCOL <= WW);

    // ---- phase 1: fused global stage + row-wise inclusive prefix ----
    for (int idx = tid; idx < NROW * 4; idx += 256) {
        const int lr  = idx >> 2;        // staged row 0..77
        const int s   = idx & 3;         // 20-col segment within the row
        const int gr  = min(max(r0 + lr - HALO, 0), HH - 1);
        const int gc0 = c0 - LHX + 20 * s;
        float v[20];
        if (xint) {
            const float* src = &x[(size_t)gr * WW + gc0];
            #pragma unroll
            for (int q = 0; q < 5; ++q) {
                const float4 t = *(const float4*)(src + 4 * q);
                v[4*q+0] = t.x; v[4*q+1] = t.y; v[4*q+2] = t.z; v[4*q+3] = t.w;
            }
        } else {
            #pragma unroll
            for (int i = 0; i < 20; ++i) {
                const int gc = min(max(gc0 + i, 0), WW - 1);
                v[i] = x[(size_t)gr * WW + gc];
            }
        }
        #pragma unroll
        for (int i = 1; i < 20; ++i) v[i] += v[i - 1];
        // 4-lane (one row) exclusive prefix of segment totals
        const float tot = v[19];
        float sum = tot;
        float u = __shfl_up(sum, 1, 4); if (s >= 1) sum += u;
        u       = __shfl_up(sum, 2, 4); if (s >= 2) sum += u;
        const float off = sum - tot;
        float* dst = &P[(lr + 1) * PSTR + 1 + 20 * s];
        #pragma unroll
        for (int i = 0; i < 20; ++i) dst[i] = v[i] + off;
    }
    __syncthreads();

    // ---- phase 2: column-wise inclusive prefix over rows 1..78 ----
    for (int idx = tid; idx < 80 * 4; idx += 256) {
        const int c  = (idx >> 2) + 1;   // col 1..80
        const int s  = idx & 3;          // row segment (20,20,20,18)
        const int rs = 1 + 20 * s;
        float v[20];
        float run = 0.0f;
        #pragma unroll
        for (int i = 0; i < 20; ++i) {
            const int r = rs + i;
            float t = P[r * PSTR + c];   // rows 79,80 are in-bounds slack
            t = (r < 79) ? t : 0.0f;     // zero out slack garbage
            run += t; v[i] = run;
        }
        const float tot = run;
        float sum = tot;
        float u = __shfl_up(sum, 1, 4); if (s >= 1) sum += u;
        u       = __shfl_up(sum, 2, 4); if (s >= 2) sum += u;
        const float off = sum - tot;
        #pragma unroll
        for (int i = 0; i < 20; ++i) {
            const int r = rs + i;
            if (r < 79) P[r * PSTR + c] = v[i] + off;
        }
    }
    __syncthreads();
    // P[a][b] = sum of staged[row < a][col < b].

    // ---- phase 3: 8 consecutive-x pixels per thread, 2 row-blocks ----
    const int g  = tid & 7;              // column group (8 groups of 8 px)
    const int ty = tid >> 3;             // 0..31
    const int B0 = 8 * g;
    #pragma unroll
    for (int j = 0; j < 2; ++j) {
        const int rr = ty + 32 * j;      // tile row
        const int A  = rr + HALO;        // staged row of the pixel
        float a[8] = {0.f,0.f,0.f,0.f,0.f,0.f,0.f,0.f};
        #pragma unroll
        for (int p = 1; p <= 7; ++p) {
            const int   k = 2 * p + 1;
            const float w = 1.0f / (7.0f * (float)(k * k));
            const float* rT = &P[(A - p) * PSTR];
            const float* rB = &P[(A + p + 1) * PSTR];
            const int cl = B0 + LHX - p;
            const int cr = cl + 2 * p + 1;
            #pragma unroll
            for (int i = 0; i < 8; ++i) {
                a[i] += w * (rB[cr + i] - rT[cr + i] - rB[cl + i] + rT[cl + i]);
            }
        }
        const int gr = r0 + rr, gc = c0 + B0;
        const float4 m0 = *(const float4*)&mask[(size_t)gr * WW + gc];
        const float4 m1 = *(const float4*)&mask[(size_t)gr * WW + gc + 4];
        float4 o0, o1;
        o0.x = a[0] * m0.x; o0.y = a[1] * m0.y; o0.z = a[2] * m0.z; o0.w = a[3] * m0.w;
        o1.x = a[4] * m1.x; o1.y = a[5] * m1.y; o1.z = a[6] * m1.z; o1.w = a[7] * m1.w;
        *(float4*)&out[(size_t)gr * WW + gc]     = o0;
        *(float4*)&out[(size_t)gr * WW + gc + 4] = o1;
    }
}

extern "C" void kernel_launch(void* const* d_in, const int* in_sizes, int n_in,
                              void* d_out, int out_size, void* d_ws, size_t ws_size,
                              hipStream_t stream) {
    const float* x    = (const float*)d_in[0];
    const float* mask = (const float*)d_in[1];
    float*       out  = (float*)d_out;
    dim3 grid(WW / TILE, HH / TILE);
    meanconv_kernel<<<grid, 256, 0, stream>>>(x, mask, out);
}